// Round 7
// baseline (1206.274 us; speedup 1.0000x reference)
//
#include <hip/hip_runtime.h>

#define HC 256    // H*C
#define CCH 64    // channels
#define NEG 0.2f

__device__ __forceinline__ float lk(float m) { return m > 0.f ? m : NEG * m; }

// ---------------- preprocessing ----------------

__global__ void deg_kernel(const int* __restrict__ dst,
                           const float* __restrict__ eattr,
                           int* __restrict__ cnt, float* __restrict__ sumf, int E) {
  int e = blockIdx.x * blockDim.x + threadIdx.x;
  if (e >= E) return;
  int d = dst[e];
  atomicAdd(&cnt[d], 1);
  atomicAdd(&sumf[d], eattr[e]);
}

// multi-block scan, stage A: per-block (1024 elems) exclusive scan + block total
__global__ __launch_bounds__(1024)
void scanA(const int* __restrict__ cnt, const float* __restrict__ sumf,
           int* __restrict__ rowptr, float* __restrict__ loopat,
           int* __restrict__ btot, int n) {
  __shared__ int wsum[16];
  int tid = threadIdx.x, lane = tid & 63, w = tid >> 6;
  int i = blockIdx.x * 1024 + tid;
  int v = (i < n) ? cnt[i] : 0;
  int s = v;
  #pragma unroll
  for (int off = 1; off < 64; off <<= 1) {
    int t = __shfl_up(s, off, 64);
    if (lane >= off) s += t;
  }
  if (lane == 63) wsum[w] = s;
  __syncthreads();
  int woff = 0;
  for (int j = 0; j < w; j++) woff += wsum[j];
  if (i < n) {
    rowptr[i] = woff + s - v;
    loopat[i] = sumf[i] / fmaxf((float)v, 1.0f);
  }
  if (tid == 1023) btot[blockIdx.x] = woff + s;
}

// stage B: single-wave scan of block totals (nb <= 64); writes rowptr[n]=total
__global__ void scanB(const int* __restrict__ btot, int* __restrict__ boff,
                      int* __restrict__ rowptr_n, int nb) {
  int lane = threadIdx.x;
  int v = (lane < nb) ? btot[lane] : 0;
  int s = v;
  #pragma unroll
  for (int off = 1; off < 64; off <<= 1) {
    int t = __shfl_up(s, off, 64);
    if (lane >= off) s += t;
  }
  if (lane < nb) boff[lane] = s - v;
  if (lane == 63) *rowptr_n = s;
}

// stage C: add block offsets
__global__ void scanC(int* __restrict__ rowptr, const int* __restrict__ boff, int n) {
  int i = blockIdx.x * blockDim.x + threadIdx.x;
  if (i < n) rowptr[i] += boff[i >> 10];
}

__global__ void csr_fill_kernel(const int* __restrict__ src,
                                const int* __restrict__ dst,
                                const float* __restrict__ eattr,
                                const int* __restrict__ rowptr,
                                int* __restrict__ fill,
                                int* __restrict__ csr_src, float* __restrict__ csr_ea, int E) {
  int e = blockIdx.x * blockDim.x + threadIdx.x;
  if (e >= E) return;
  int d = dst[e];
  int p = atomicAdd(&fill[d], 1);
  int slot = rowptr[d] + p;
  csr_src[slot] = src[e];
  csr_ea[slot] = eattr[e];
}

// ---------------- fp32 GEMM: 128x128 tile, 8x8 microtile, reg-prefetch pipeline ----
// grid.x: 0,1 -> Wl panels; 2,3 -> Wr panels. bn = (x&1)*128.
// xl = A@Wl+bl, xr = A@Wr+br (A is [nrows][K], W is [K][256]).

__global__ __launch_bounds__(256, 4)
void gemm128(const float* __restrict__ A,
             const float* __restrict__ Wl, const float* __restrict__ bl,
             const float* __restrict__ Wr, const float* __restrict__ br,
             float* __restrict__ xl, float* __restrict__ xr,
             int nrows, int K) {
  __shared__ float As[16][132];   // [k][m]
  __shared__ float Ws[16][132];   // [k][n]
  const float* W; const float* bb; float* out;
  if (blockIdx.x < 2) { W = Wl; bb = bl; out = xl; }
  else                { W = Wr; bb = br; out = xr; }
  int bn = (blockIdx.x & 1) * 128;
  int bm = blockIdx.y * 128;
  int tid = threadIdx.x;
  int tx = tid & 15, ty = tid >> 4;
  int arow = tid & 127;              // A tile row this thread stages
  int akk  = (tid >> 7) * 8;         // 0 or 8
  int wkk  = tid >> 4;               // 0..15 (k-row of W)
  int wc   = (tid & 15) * 4;         // 0..60

  int row0 = bm + arow;
  bool aval = row0 < nrows;
  const float* arp = A + (size_t)row0 * K + akk;
  const float* wrp = W + (size_t)wkk * HC + bn + wc;

  float4 z = make_float4(0.f, 0.f, 0.f, 0.f);
  float4 a0 = aval ? *(const float4*)arp       : z;
  float4 a1 = aval ? *(const float4*)(arp + 4) : z;
  float4 w0 = *(const float4*)wrp;
  float4 w1 = *(const float4*)(wrp + 64);

  float acc[8][8] = {};
  int k0 = 0;
  while (true) {
    As[akk+0][arow] = a0.x; As[akk+1][arow] = a0.y;
    As[akk+2][arow] = a0.z; As[akk+3][arow] = a0.w;
    As[akk+4][arow] = a1.x; As[akk+5][arow] = a1.y;
    As[akk+6][arow] = a1.z; As[akk+7][arow] = a1.w;
    *(float4*)&Ws[wkk][wc]      = w0;
    *(float4*)&Ws[wkk][wc + 64] = w1;
    __syncthreads();
    k0 += 16;
    bool more = k0 < K;
    if (more) {
      a0 = aval ? *(const float4*)(arp + k0)     : z;
      a1 = aval ? *(const float4*)(arp + k0 + 4) : z;
      w0 = *(const float4*)(wrp + (size_t)k0 * HC);
      w1 = *(const float4*)(wrp + (size_t)k0 * HC + 64);
    }
    #pragma unroll
    for (int k = 0; k < 16; k++) {
      float av[8], wv[8];
      *(float4*)&av[0] = *(const float4*)&As[k][ty * 8];
      *(float4*)&av[4] = *(const float4*)&As[k][ty * 8 + 4];
      *(float4*)&wv[0] = *(const float4*)&Ws[k][tx * 4];
      *(float4*)&wv[4] = *(const float4*)&Ws[k][tx * 4 + 64];
      #pragma unroll
      for (int i = 0; i < 8; i++)
        #pragma unroll
        for (int j = 0; j < 8; j++)
          acc[i][j] = fmaf(av[i], wv[j], acc[i][j]);
    }
    if (!more) break;
    __syncthreads();
  }

  float4 bv0 = *(const float4*)(bb + bn + tx * 4);
  float4 bv1 = *(const float4*)(bb + bn + tx * 4 + 64);
  #pragma unroll
  for (int i = 0; i < 8; i++) {
    int row = bm + ty * 8 + i;
    if (row < nrows) {
      float* op = out + (size_t)row * HC + bn + tx * 4;
      float4 o0, o1;
      o0.x = acc[i][0] + bv0.x; o0.y = acc[i][1] + bv0.y;
      o0.z = acc[i][2] + bv0.z; o0.w = acc[i][3] + bv0.w;
      o1.x = acc[i][4] + bv1.x; o1.y = acc[i][5] + bv1.y;
      o1.z = acc[i][6] + bv1.z; o1.w = acc[i][7] + bv1.w;
      *(float4*)op        = o0;
      *(float4*)(op + 64) = o1;
    }
  }
}

// ---------------- edge phase (unchanged from R6) ----------------
// block = node (4 waves). Each WAVE processes a contiguous quarter of the
// node's edge list, handling the WHOLE edge (all 4 heads): lane l holds
// channels 4l..4l+3 (float4), head h = l>>4.

template<int B>
__device__ __forceinline__ void proc_edges(
    const float* __restrict__ xl, int i,
    const int* __restrict__ csr_src, const float* __restrict__ csr_ea,
    const float4 xr4, const float4 we4, const float4 ah4, int l4,
    float& mx, float& den, float4& acc) {
  int sn[B]; float ea[B]; float4 v[B]; float s[B];
  #pragma unroll
  for (int j = 0; j < B; j++) { sn[j] = csr_src[i + j]; ea[j] = csr_ea[i + j]; }
  #pragma unroll
  for (int j = 0; j < B; j++)
    v[j] = *(const float4*)(xl + (size_t)sn[j] * HC + l4);
  #pragma unroll
  for (int j = 0; j < B; j++) {
    float mx_ = fmaf(ea[j], we4.x, v[j].x + xr4.x);
    float my_ = fmaf(ea[j], we4.y, v[j].y + xr4.y);
    float mz_ = fmaf(ea[j], we4.z, v[j].z + xr4.z);
    float mw_ = fmaf(ea[j], we4.w, v[j].w + xr4.w);
    s[j] = lk(mx_) * ah4.x + lk(my_) * ah4.y + lk(mz_) * ah4.z + lk(mw_) * ah4.w;
  }
  #pragma unroll
  for (int off = 8; off >= 1; off >>= 1)
    #pragma unroll
    for (int j = 0; j < B; j++) s[j] += __shfl_xor(s[j], off, 64);
  float bm = s[0];
  #pragma unroll
  for (int j = 1; j < B; j++) bm = fmaxf(bm, s[j]);
  float newm = fmaxf(mx, bm);
  float r = __expf(mx - newm);
  den *= r; acc.x *= r; acc.y *= r; acc.z *= r; acc.w *= r;
  #pragma unroll
  for (int j = 0; j < B; j++) {
    float p = __expf(s[j] - newm);
    den += p;
    acc.x = fmaf(p, v[j].x, acc.x);
    acc.y = fmaf(p, v[j].y, acc.y);
    acc.z = fmaf(p, v[j].z, acc.z);
    acc.w = fmaf(p, v[j].w, acc.w);
  }
  mx = newm;
}

__global__ __launch_bounds__(256)
void gat_edge(const float* __restrict__ xl, const float* __restrict__ xr,
              const float* __restrict__ loopat, const int* __restrict__ rowptr,
              const int* __restrict__ csr_src, const float* __restrict__ csr_ea,
              const float* __restrict__ We, const float* __restrict__ att,
              const float* __restrict__ bias, const float* __restrict__ prelu_w,
              float* __restrict__ out, int n, int is_last) {
  int node = blockIdx.x;
  int l    = threadIdx.x & 63;
  int wv   = threadIdx.x >> 6;
  int l4   = l * 4;
  float4 we4 = *(const float4*)(We + l4);
  float4 ah4 = *(const float4*)(att + l4);
  float4 xr4 = *(const float4*)(xr + (size_t)node * HC + l4);

  float mx, den; float4 acc;
  if (wv == 0) {
    float4 vs = *(const float4*)(xl + (size_t)node * HC + l4);
    float la = loopat[node];
    float mx_ = fmaf(la, we4.x, vs.x + xr4.x);
    float my_ = fmaf(la, we4.y, vs.y + xr4.y);
    float mz_ = fmaf(la, we4.z, vs.z + xr4.z);
    float mw_ = fmaf(la, we4.w, vs.w + xr4.w);
    float t = lk(mx_) * ah4.x + lk(my_) * ah4.y + lk(mz_) * ah4.z + lk(mw_) * ah4.w;
    #pragma unroll
    for (int off = 8; off >= 1; off >>= 1) t += __shfl_xor(t, off, 64);
    mx = t; den = 1.f; acc = vs;
  } else {
    mx = -3.4e38f; den = 0.f; acc = make_float4(0.f, 0.f, 0.f, 0.f);
  }

  int beg = rowptr[node], end = rowptr[node + 1];
  int per = (end - beg + 3) >> 2;
  int wbeg = beg + wv * per;
  int wend = min(wbeg + per, end);
  int i = wbeg;
  for (; i + 4 <= wend; i += 4)
    proc_edges<4>(xl, i, csr_src, csr_ea, xr4, we4, ah4, l4, mx, den, acc);
  for (; i < wend; i++)
    proc_edges<1>(xl, i, csr_src, csr_ea, xr4, we4, ah4, l4, mx, den, acc);

  __shared__ float  s_mx[4][4];
  __shared__ float  s_den[4][4];
  __shared__ float4 s_acc[4][64];
  int h = l >> 4;
  s_acc[wv][l] = acc;
  if ((l & 15) == 0) { s_mx[wv][h] = mx; s_den[wv][h] = den; }
  __syncthreads();
  if (wv == 0) {
    float M = fmaxf(fmaxf(s_mx[0][h], s_mx[1][h]), fmaxf(s_mx[2][h], s_mx[3][h]));
    float dt = 0.f;
    float4 a = make_float4(0.f, 0.f, 0.f, 0.f);
    #pragma unroll
    for (int w = 0; w < 4; w++) {
      float f = __expf(s_mx[w][h] - M);
      dt = fmaf(s_den[w][h], f, dt);
      float4 aw = s_acc[w][l];
      a.x = fmaf(aw.x, f, a.x);
      a.y = fmaf(aw.y, f, a.y);
      a.z = fmaf(aw.z, f, a.z);
      a.w = fmaf(aw.w, f, a.w);
    }
    float inv = 1.f / (dt + 1e-16f);
    a.x *= inv; a.y *= inv; a.z *= inv; a.w *= inv;
    a.x += __shfl_xor(a.x, 16, 64); a.x += __shfl_xor(a.x, 32, 64);
    a.y += __shfl_xor(a.y, 16, 64); a.y += __shfl_xor(a.y, 32, 64);
    a.z += __shfl_xor(a.z, 16, 64); a.z += __shfl_xor(a.z, 32, 64);
    a.w += __shfl_xor(a.w, 16, 64); a.w += __shfl_xor(a.w, 32, 64);
    if (l < 16) {
      int c = l * 4;
      float4 bv = *(const float4*)(bias + c);
      float4 o;
      o.x = 0.25f * a.x + bv.x;
      o.y = 0.25f * a.y + bv.y;
      o.z = 0.25f * a.z + bv.z;
      o.w = 0.25f * a.w + bv.w;
      if (is_last) {
        float4 pw = *(const float4*)(prelu_w + c);
        o.x = o.x >= 0.f ? o.x : pw.x * o.x;
        o.y = o.y >= 0.f ? o.y : pw.y * o.y;
        o.z = o.z >= 0.f ? o.z : pw.z * o.z;
        o.w = o.w >= 0.f ? o.w : pw.w * o.w;
      }
      *(float4*)(out + (size_t)node * CCH + c) = o;
    }
  }
}

// ---------------- launch ----------------

extern "C" void kernel_launch(void* const* d_in, const int* in_sizes, int n_in,
                              void* d_out, int out_size, void* d_ws, size_t ws_size,
                              hipStream_t stream) {
  const float* x     = (const float*)d_in[0];
  const int*   ei    = (const int*)d_in[1];     // int32
  const float* eattr = (const float*)d_in[2];
  int N = in_sizes[0] / HC;        // 50000
  int E = in_sizes[1] / 2;         // 800000
  const int* src = ei;
  const int* dst = ei + E;

  const float* Wl[3]  = {(const float*)d_in[3],  (const float*)d_in[10], (const float*)d_in[17]};
  const float* bl[3]  = {(const float*)d_in[4],  (const float*)d_in[11], (const float*)d_in[18]};
  const float* Wr[3]  = {(const float*)d_in[5],  (const float*)d_in[12], (const float*)d_in[19]};
  const float* br[3]  = {(const float*)d_in[6],  (const float*)d_in[13], (const float*)d_in[20]};
  const float* Wev[3] = {(const float*)d_in[7],  (const float*)d_in[14], (const float*)d_in[21]};
  const float* attv[3]= {(const float*)d_in[8],  (const float*)d_in[15], (const float*)d_in[22]};
  const float* bias[3]= {(const float*)d_in[9],  (const float*)d_in[16], (const float*)d_in[23]};
  const float* prelu  = (const float*)d_in[24];

  char* p = (char*)d_ws;
  float* xl     = (float*)p; p += (size_t)N * HC * 4;
  float* xr     = (float*)p; p += (size_t)N * HC * 4;
  float* hbuf   = (float*)p; p += (size_t)N * CCH * 4;
  int*   cnt    = (int*)p;   p += (size_t)N * 4;
  int*   fill   = (int*)p;   p += (size_t)N * 4;
  float* sumf   = (float*)p; p += (size_t)N * 4;
  float* loopat = (float*)p; p += (size_t)N * 4;
  int*   rowptr = (int*)p;   p += (size_t)(N + 8) * 4;
  int*   btot   = (int*)p;   p += 64 * 4;
  int*   boff   = (int*)p;   p += 64 * 4;
  int*   csr_src= (int*)p;   p += (size_t)E * 4;
  float* csr_ea = (float*)p; p += (size_t)E * 4;

  hipMemsetAsync(cnt, 0, (size_t)N * 3 * 4, stream);

  int tb = 256;
  int nb = (N + 1023) / 1024;     // 49 (must be <= 64)
  deg_kernel<<<dim3((E + tb - 1) / tb), dim3(tb), 0, stream>>>(dst, eattr, cnt, sumf, E);
  scanA<<<dim3(nb), dim3(1024), 0, stream>>>(cnt, sumf, rowptr, loopat, btot, N);
  scanB<<<dim3(1), dim3(64), 0, stream>>>(btot, boff, rowptr + N, nb);
  scanC<<<dim3((N + tb - 1) / tb), dim3(tb), 0, stream>>>(rowptr, boff, N);
  csr_fill_kernel<<<dim3((E + tb - 1) / tb), dim3(tb), 0, stream>>>(src, dst, eattr, rowptr,
                                                                    fill, csr_src, csr_ea, E);

  const float* in = x;
  int K = 256;
  for (int l = 0; l < 3; l++) {
    dim3 g(4, (N + 127) / 128);
    gemm128<<<g, dim3(256), 0, stream>>>(in, Wl[l], bl[l], Wr[l], br[l], xl, xr, N, K);
    float* o = (l == 2) ? (float*)d_out : hbuf;
    gat_edge<<<dim3(N), dim3(256), 0, stream>>>(xl, xr, loopat, rowptr, csr_src, csr_ea,
                                                Wev[l], attv[l], bias[l], prelu, o, N, l == 2);
    in = hbuf;
    K = CCH;
  }
}

// Round 8
// 896.633 us; speedup vs baseline: 1.3453x; 1.3453x over previous
//
#include <hip/hip_runtime.h>

#define HC 256    // H*C
#define CCH 64    // channels
#define NEG 0.2f

__device__ __forceinline__ float lk(float m) { return m > 0.f ? m : NEG * m; }

// ---------------- preprocessing ----------------

__global__ void deg_kernel(const int* __restrict__ dst,
                           const float* __restrict__ eattr,
                           int* __restrict__ cnt, float* __restrict__ sumf, int E) {
  int e = blockIdx.x * blockDim.x + threadIdx.x;
  if (e >= E) return;
  int d = dst[e];
  atomicAdd(&cnt[d], 1);
  atomicAdd(&sumf[d], eattr[e]);
}

// multi-block scan, stage A: per-block (1024 elems) exclusive scan + block total
__global__ __launch_bounds__(1024)
void scanA(const int* __restrict__ cnt, const float* __restrict__ sumf,
           int* __restrict__ rowptr, float* __restrict__ loopat,
           int* __restrict__ btot, int n) {
  __shared__ int wsum[16];
  int tid = threadIdx.x, lane = tid & 63, w = tid >> 6;
  int i = blockIdx.x * 1024 + tid;
  int v = (i < n) ? cnt[i] : 0;
  int s = v;
  #pragma unroll
  for (int off = 1; off < 64; off <<= 1) {
    int t = __shfl_up(s, off, 64);
    if (lane >= off) s += t;
  }
  if (lane == 63) wsum[w] = s;
  __syncthreads();
  int woff = 0;
  for (int j = 0; j < w; j++) woff += wsum[j];
  if (i < n) {
    rowptr[i] = woff + s - v;
    loopat[i] = sumf[i] / fmaxf((float)v, 1.0f);
  }
  if (tid == 1023) btot[blockIdx.x] = woff + s;
}

// stage B: single-wave scan of block totals (nb <= 64); writes rowptr[n]=total
__global__ void scanB(const int* __restrict__ btot, int* __restrict__ boff,
                      int* __restrict__ rowptr_n, int nb) {
  int lane = threadIdx.x;
  int v = (lane < nb) ? btot[lane] : 0;
  int s = v;
  #pragma unroll
  for (int off = 1; off < 64; off <<= 1) {
    int t = __shfl_up(s, off, 64);
    if (lane >= off) s += t;
  }
  if (lane < nb) boff[lane] = s - v;
  if (lane == 63) *rowptr_n = s;
}

// stage C: add block offsets
__global__ void scanC(int* __restrict__ rowptr, const int* __restrict__ boff, int n) {
  int i = blockIdx.x * blockDim.x + threadIdx.x;
  if (i < n) rowptr[i] += boff[i >> 10];
}

__global__ void csr_fill_kernel(const int* __restrict__ src,
                                const int* __restrict__ dst,
                                const float* __restrict__ eattr,
                                const int* __restrict__ rowptr,
                                int* __restrict__ fill,
                                int* __restrict__ csr_src, float* __restrict__ csr_ea, int E) {
  int e = blockIdx.x * blockDim.x + threadIdx.x;
  if (e >= E) return;
  int d = dst[e];
  int p = atomicAdd(&fill[d], 1);
  int slot = rowptr[d] + p;
  csr_src[slot] = src[e];
  csr_ea[slot] = eattr[e];
}

// ---------------- fp32 GEMM: 128x128 tile, 8x8 microtile, reg-prefetch pipeline ----
// grid.x: 0,1 -> Wl panels; 2,3 -> Wr panels. bn = (x&1)*128.
// All accumulator/fragment state in named float4s (no address-taken arrays,
// no runtime indexing) -> guaranteed register allocation. VGPR ~110, cap 170.

__device__ __forceinline__ void fma8(float a, const float4 blo, const float4 bhi,
                                     float4& c0, float4& c1) {
  c0.x = fmaf(a, blo.x, c0.x); c0.y = fmaf(a, blo.y, c0.y);
  c0.z = fmaf(a, blo.z, c0.z); c0.w = fmaf(a, blo.w, c0.w);
  c1.x = fmaf(a, bhi.x, c1.x); c1.y = fmaf(a, bhi.y, c1.y);
  c1.z = fmaf(a, bhi.z, c1.z); c1.w = fmaf(a, bhi.w, c1.w);
}

__global__ __launch_bounds__(256, 3)
void gemm128(const float* __restrict__ A,
             const float* __restrict__ Wl, const float* __restrict__ bl,
             const float* __restrict__ Wr, const float* __restrict__ br,
             float* __restrict__ xl, float* __restrict__ xr,
             int nrows, int K) {
  __shared__ float As[16][132];   // [k][m]
  __shared__ float Ws[16][132];   // [k][n]
  const float* W; const float* bb; float* out;
  if (blockIdx.x < 2) { W = Wl; bb = bl; out = xl; }
  else                { W = Wr; bb = br; out = xr; }
  int bn = (blockIdx.x & 1) * 128;
  int bm = blockIdx.y * 128;
  int tid = threadIdx.x;
  int tx = tid & 15, ty = tid >> 4;
  int arow = tid & 127;              // A tile row this thread stages
  int akk  = (tid >> 7) * 8;         // 0 or 8
  int wkk  = tid >> 4;               // 0..15 (k-row of W)
  int wc   = (tid & 15) * 4;         // 0..60

  int row0 = bm + arow;
  bool aval = row0 < nrows;
  const float* arp = A + (size_t)row0 * K + akk;
  const float* wrp = W + (size_t)wkk * HC + bn + wc;

  float4 z = make_float4(0.f, 0.f, 0.f, 0.f);
  float4 a0 = aval ? *(const float4*)arp       : z;
  float4 a1 = aval ? *(const float4*)(arp + 4) : z;
  float4 w0 = *(const float4*)wrp;
  float4 w1 = *(const float4*)(wrp + 64);

  float4 c0[8], c1[8];
  #pragma unroll
  for (int i = 0; i < 8; i++) { c0[i] = z; c1[i] = z; }

  int k0 = 0;
  while (true) {
    As[akk+0][arow] = a0.x; As[akk+1][arow] = a0.y;
    As[akk+2][arow] = a0.z; As[akk+3][arow] = a0.w;
    As[akk+4][arow] = a1.x; As[akk+5][arow] = a1.y;
    As[akk+6][arow] = a1.z; As[akk+7][arow] = a1.w;
    *(float4*)&Ws[wkk][wc]      = w0;
    *(float4*)&Ws[wkk][wc + 64] = w1;
    __syncthreads();
    k0 += 16;
    bool more = k0 < K;
    if (more) {
      a0 = aval ? *(const float4*)(arp + k0)     : z;
      a1 = aval ? *(const float4*)(arp + k0 + 4) : z;
      w0 = *(const float4*)(wrp + (size_t)k0 * HC);
      w1 = *(const float4*)(wrp + (size_t)k0 * HC + 64);
    }
    #pragma unroll
    for (int k = 0; k < 16; k++) {
      float4 alo = *(const float4*)&As[k][ty * 8];
      float4 ahi = *(const float4*)&As[k][ty * 8 + 4];
      float4 blo = *(const float4*)&Ws[k][tx * 4];
      float4 bhi = *(const float4*)&Ws[k][tx * 4 + 64];
      fma8(alo.x, blo, bhi, c0[0], c1[0]);
      fma8(alo.y, blo, bhi, c0[1], c1[1]);
      fma8(alo.z, blo, bhi, c0[2], c1[2]);
      fma8(alo.w, blo, bhi, c0[3], c1[3]);
      fma8(ahi.x, blo, bhi, c0[4], c1[4]);
      fma8(ahi.y, blo, bhi, c0[5], c1[5]);
      fma8(ahi.z, blo, bhi, c0[6], c1[6]);
      fma8(ahi.w, blo, bhi, c0[7], c1[7]);
    }
    if (!more) break;
    __syncthreads();
  }

  float4 bv0 = *(const float4*)(bb + bn + tx * 4);
  float4 bv1 = *(const float4*)(bb + bn + tx * 4 + 64);
  #pragma unroll
  for (int i = 0; i < 8; i++) {
    int row = bm + ty * 8 + i;
    if (row < nrows) {
      float* op = out + (size_t)row * HC + bn + tx * 4;
      float4 o0, o1;
      o0.x = c0[i].x + bv0.x; o0.y = c0[i].y + bv0.y;
      o0.z = c0[i].z + bv0.z; o0.w = c0[i].w + bv0.w;
      o1.x = c1[i].x + bv1.x; o1.y = c1[i].y + bv1.y;
      o1.z = c1[i].z + bv1.z; o1.w = c1[i].w + bv1.w;
      *(float4*)op        = o0;
      *(float4*)(op + 64) = o1;
    }
  }
}

// ---------------- edge phase (unchanged) ----------------
// block = node (4 waves). Each WAVE processes a contiguous quarter of the
// node's edge list, handling the WHOLE edge (all 4 heads): lane l holds
// channels 4l..4l+3 (float4), head h = l>>4.

template<int B>
__device__ __forceinline__ void proc_edges(
    const float* __restrict__ xl, int i,
    const int* __restrict__ csr_src, const float* __restrict__ csr_ea,
    const float4 xr4, const float4 we4, const float4 ah4, int l4,
    float& mx, float& den, float4& acc) {
  int sn[B]; float ea[B]; float4 v[B]; float s[B];
  #pragma unroll
  for (int j = 0; j < B; j++) { sn[j] = csr_src[i + j]; ea[j] = csr_ea[i + j]; }
  #pragma unroll
  for (int j = 0; j < B; j++)
    v[j] = *(const float4*)(xl + (size_t)sn[j] * HC + l4);
  #pragma unroll
  for (int j = 0; j < B; j++) {
    float mx_ = fmaf(ea[j], we4.x, v[j].x + xr4.x);
    float my_ = fmaf(ea[j], we4.y, v[j].y + xr4.y);
    float mz_ = fmaf(ea[j], we4.z, v[j].z + xr4.z);
    float mw_ = fmaf(ea[j], we4.w, v[j].w + xr4.w);
    s[j] = lk(mx_) * ah4.x + lk(my_) * ah4.y + lk(mz_) * ah4.z + lk(mw_) * ah4.w;
  }
  #pragma unroll
  for (int off = 8; off >= 1; off >>= 1)
    #pragma unroll
    for (int j = 0; j < B; j++) s[j] += __shfl_xor(s[j], off, 64);
  float bm = s[0];
  #pragma unroll
  for (int j = 1; j < B; j++) bm = fmaxf(bm, s[j]);
  float newm = fmaxf(mx, bm);
  float r = __expf(mx - newm);
  den *= r; acc.x *= r; acc.y *= r; acc.z *= r; acc.w *= r;
  #pragma unroll
  for (int j = 0; j < B; j++) {
    float p = __expf(s[j] - newm);
    den += p;
    acc.x = fmaf(p, v[j].x, acc.x);
    acc.y = fmaf(p, v[j].y, acc.y);
    acc.z = fmaf(p, v[j].z, acc.z);
    acc.w = fmaf(p, v[j].w, acc.w);
  }
  mx = newm;
}

__global__ __launch_bounds__(256)
void gat_edge(const float* __restrict__ xl, const float* __restrict__ xr,
              const float* __restrict__ loopat, const int* __restrict__ rowptr,
              const int* __restrict__ csr_src, const float* __restrict__ csr_ea,
              const float* __restrict__ We, const float* __restrict__ att,
              const float* __restrict__ bias, const float* __restrict__ prelu_w,
              float* __restrict__ out, int n, int is_last) {
  int node = blockIdx.x;
  int l    = threadIdx.x & 63;
  int wv   = threadIdx.x >> 6;
  int l4   = l * 4;
  float4 we4 = *(const float4*)(We + l4);
  float4 ah4 = *(const float4*)(att + l4);
  float4 xr4 = *(const float4*)(xr + (size_t)node * HC + l4);

  float mx, den; float4 acc;
  if (wv == 0) {
    float4 vs = *(const float4*)(xl + (size_t)node * HC + l4);
    float la = loopat[node];
    float mx_ = fmaf(la, we4.x, vs.x + xr4.x);
    float my_ = fmaf(la, we4.y, vs.y + xr4.y);
    float mz_ = fmaf(la, we4.z, vs.z + xr4.z);
    float mw_ = fmaf(la, we4.w, vs.w + xr4.w);
    float t = lk(mx_) * ah4.x + lk(my_) * ah4.y + lk(mz_) * ah4.z + lk(mw_) * ah4.w;
    #pragma unroll
    for (int off = 8; off >= 1; off >>= 1) t += __shfl_xor(t, off, 64);
    mx = t; den = 1.f; acc = vs;
  } else {
    mx = -3.4e38f; den = 0.f; acc = make_float4(0.f, 0.f, 0.f, 0.f);
  }

  int beg = rowptr[node], end = rowptr[node + 1];
  int per = (end - beg + 3) >> 2;
  int wbeg = beg + wv * per;
  int wend = min(wbeg + per, end);
  int i = wbeg;
  for (; i + 4 <= wend; i += 4)
    proc_edges<4>(xl, i, csr_src, csr_ea, xr4, we4, ah4, l4, mx, den, acc);
  for (; i < wend; i++)
    proc_edges<1>(xl, i, csr_src, csr_ea, xr4, we4, ah4, l4, mx, den, acc);

  __shared__ float  s_mx[4][4];
  __shared__ float  s_den[4][4];
  __shared__ float4 s_acc[4][64];
  int h = l >> 4;
  s_acc[wv][l] = acc;
  if ((l & 15) == 0) { s_mx[wv][h] = mx; s_den[wv][h] = den; }
  __syncthreads();
  if (wv == 0) {
    float M = fmaxf(fmaxf(s_mx[0][h], s_mx[1][h]), fmaxf(s_mx[2][h], s_mx[3][h]));
    float dt = 0.f;
    float4 a = make_float4(0.f, 0.f, 0.f, 0.f);
    #pragma unroll
    for (int w = 0; w < 4; w++) {
      float f = __expf(s_mx[w][h] - M);
      dt = fmaf(s_den[w][h], f, dt);
      float4 aw = s_acc[w][l];
      a.x = fmaf(aw.x, f, a.x);
      a.y = fmaf(aw.y, f, a.y);
      a.z = fmaf(aw.z, f, a.z);
      a.w = fmaf(aw.w, f, a.w);
    }
    float inv = 1.f / (dt + 1e-16f);
    a.x *= inv; a.y *= inv; a.z *= inv; a.w *= inv;
    a.x += __shfl_xor(a.x, 16, 64); a.x += __shfl_xor(a.x, 32, 64);
    a.y += __shfl_xor(a.y, 16, 64); a.y += __shfl_xor(a.y, 32, 64);
    a.z += __shfl_xor(a.z, 16, 64); a.z += __shfl_xor(a.z, 32, 64);
    a.w += __shfl_xor(a.w, 16, 64); a.w += __shfl_xor(a.w, 32, 64);
    if (l < 16) {
      int c = l * 4;
      float4 bv = *(const float4*)(bias + c);
      float4 o;
      o.x = 0.25f * a.x + bv.x;
      o.y = 0.25f * a.y + bv.y;
      o.z = 0.25f * a.z + bv.z;
      o.w = 0.25f * a.w + bv.w;
      if (is_last) {
        float4 pw = *(const float4*)(prelu_w + c);
        o.x = o.x >= 0.f ? o.x : pw.x * o.x;
        o.y = o.y >= 0.f ? o.y : pw.y * o.y;
        o.z = o.z >= 0.f ? o.z : pw.z * o.z;
        o.w = o.w >= 0.f ? o.w : pw.w * o.w;
      }
      *(float4*)(out + (size_t)node * CCH + c) = o;
    }
  }
}

// ---------------- launch ----------------

extern "C" void kernel_launch(void* const* d_in, const int* in_sizes, int n_in,
                              void* d_out, int out_size, void* d_ws, size_t ws_size,
                              hipStream_t stream) {
  const float* x     = (const float*)d_in[0];
  const int*   ei    = (const int*)d_in[1];     // int32
  const float* eattr = (const float*)d_in[2];
  int N = in_sizes[0] / HC;        // 50000
  int E = in_sizes[1] / 2;         // 800000
  const int* src = ei;
  const int* dst = ei + E;

  const float* Wl[3]  = {(const float*)d_in[3],  (const float*)d_in[10], (const float*)d_in[17]};
  const float* bl[3]  = {(const float*)d_in[4],  (const float*)d_in[11], (const float*)d_in[18]};
  const float* Wr[3]  = {(const float*)d_in[5],  (const float*)d_in[12], (const float*)d_in[19]};
  const float* br[3]  = {(const float*)d_in[6],  (const float*)d_in[13], (const float*)d_in[20]};
  const float* Wev[3] = {(const float*)d_in[7],  (const float*)d_in[14], (const float*)d_in[21]};
  const float* attv[3]= {(const float*)d_in[8],  (const float*)d_in[15], (const float*)d_in[22]};
  const float* bias[3]= {(const float*)d_in[9],  (const float*)d_in[16], (const float*)d_in[23]};
  const float* prelu  = (const float*)d_in[24];

  char* p = (char*)d_ws;
  float* xl     = (float*)p; p += (size_t)N * HC * 4;
  float* xr     = (float*)p; p += (size_t)N * HC * 4;
  float* hbuf   = (float*)p; p += (size_t)N * CCH * 4;
  int*   cnt    = (int*)p;   p += (size_t)N * 4;
  int*   fill   = (int*)p;   p += (size_t)N * 4;
  float* sumf   = (float*)p; p += (size_t)N * 4;
  float* loopat = (float*)p; p += (size_t)N * 4;
  int*   rowptr = (int*)p;   p += (size_t)(N + 8) * 4;
  int*   btot   = (int*)p;   p += 64 * 4;
  int*   boff   = (int*)p;   p += 64 * 4;
  int*   csr_src= (int*)p;   p += (size_t)E * 4;
  float* csr_ea = (float*)p; p += (size_t)E * 4;

  hipMemsetAsync(cnt, 0, (size_t)N * 3 * 4, stream);

  int tb = 256;
  int nb = (N + 1023) / 1024;     // 49 (must be <= 64)
  deg_kernel<<<dim3((E + tb - 1) / tb), dim3(tb), 0, stream>>>(dst, eattr, cnt, sumf, E);
  scanA<<<dim3(nb), dim3(1024), 0, stream>>>(cnt, sumf, rowptr, loopat, btot, N);
  scanB<<<dim3(1), dim3(64), 0, stream>>>(btot, boff, rowptr + N, nb);
  scanC<<<dim3((N + tb - 1) / tb), dim3(tb), 0, stream>>>(rowptr, boff, N);
  csr_fill_kernel<<<dim3((E + tb - 1) / tb), dim3(tb), 0, stream>>>(src, dst, eattr, rowptr,
                                                                    fill, csr_src, csr_ea, E);

  const float* in = x;
  int K = 256;
  for (int l = 0; l < 3; l++) {
    dim3 g(4, (N + 127) / 128);
    gemm128<<<g, dim3(256), 0, stream>>>(in, Wl[l], bl[l], Wr[l], br[l], xl, xr, N, K);
    float* o = (l == 2) ? (float*)d_out : hbuf;
    gat_edge<<<dim3(N), dim3(256), 0, stream>>>(xl, xr, loopat, rowptr, csr_src, csr_ea,
                                                Wev[l], attv[l], bias[l], prelu, o, N, l == 2);
    in = hbuf;
    K = CCH;
  }
}